// Round 13
// baseline (204.308 us; speedup 1.0000x reference)
//
#include <hip/hip_runtime.h>
#include <math.h>

#define BB 16
#define GG 512
#define PP 512
#define EE 256
#define HH 16
#define KD 16
#define HK 256

typedef __bf16 bf16x8 __attribute__((ext_vector_type(8)));
typedef __bf16 bf16x4 __attribute__((ext_vector_type(4)));
typedef float f32x4 __attribute__((ext_vector_type(4)));
typedef float f32x16 __attribute__((ext_vector_type(16)));

// LDS geometry for fused_proj (bytes): compute phase 30720, epilogue 29184.
#define SA_STRIDE 40           // 32 cols + 8 pad (80B rows: 16B-aligned, <=4-way banks)
#define SMEM_BYTES 30720

__device__ inline void cvt_split8(const float* __restrict__ p, bf16x8& h, bf16x8& l)
{
    float4 f0 = *(const float4*)p;
    float4 f1 = *(const float4*)(p + 4);
    float v[8] = {f0.x, f0.y, f0.z, f0.w, f1.x, f1.y, f1.z, f1.w};
#pragma unroll
    for (int j = 0; j < 8; ++j) {
        __bf16 hh = (__bf16)v[j];
        h[j] = hh;
        l[j] = (__bf16)(v[j] - (float)hh);
    }
}

// ---------------------------------------------------------------------------
// All four weight transpose+splits in one launch.
// ---------------------------------------------------------------------------
__global__ __launch_bounds__(256) void weight_prep(const float* __restrict__ Wk,
                                                   const float* __restrict__ Wv,
                                                   const float* __restrict__ Wq,
                                                   const float* __restrict__ Wc,
                                                   __bf16* __restrict__ wkt_h, __bf16* __restrict__ wkt_l,
                                                   __bf16* __restrict__ wvt_h, __bf16* __restrict__ wvt_l,
                                                   __bf16* __restrict__ wqt_h, __bf16* __restrict__ wqt_l,
                                                   __bf16* __restrict__ wct_h, __bf16* __restrict__ wct_l)
{
    int id = blockIdx.x * 256 + threadIdx.x;
    const float* W;
    __bf16 *th, *tl;
    int kbits;
    if (id < 65536)       { W = Wk; th = wkt_h; tl = wkt_l; kbits = 8; }
    else if (id < 131072) { id -= 65536;  W = Wv; th = wvt_h; tl = wvt_l; kbits = 8; }
    else if (id < 262144) { id -= 131072; W = Wq; th = wqt_h; tl = wqt_l; kbits = 9; }
    else                  { id -= 262144; W = Wc; th = wct_h; tl = wct_l; kbits = 8; }
    const int Kd = 1 << kbits;
    const int k = id & (Kd - 1);
    const int n = id >> kbits;
    const float v = W[(size_t)k * HK + n];
    const __bf16 h = (__bf16)v;
    th[((size_t)n << kbits) + k] = h;
    tl[((size_t)n << kbits) + k] = (__bf16)(v - (float)h);
}

// ---------------------------------------------------------------------------
// LDS-staged fused K/V projection body (verified round 10) + enc hi/lo split
// emitted from the staging registers (n0==0 blocks only; no extra pass).
// ---------------------------------------------------------------------------
__device__ inline void kvproj_body(int bx, int tid, unsigned char* smem,
                                   const float* __restrict__ A,
                                   const __bf16* __restrict__ Bkh,
                                   const __bf16* __restrict__ Bkl,
                                   const __bf16* __restrict__ Bvh,
                                   const __bf16* __restrict__ Bvl,
                                   __bf16* __restrict__ Khi,
                                   __bf16* __restrict__ Klo,
                                   __bf16* __restrict__ Vt,
                                   __bf16* __restrict__ enc_h,
                                   __bf16* __restrict__ enc_l)
{
    __bf16* sAh = (__bf16*)smem;               // [64][SA_STRIDE]
    __bf16* sAl = sAh + 64 * SA_STRIDE;
    __bf16* sB  = sAl + 64 * SA_STRIDE;        // [4][64][SA_STRIDE]

    const int lane = tid & 63;
    const int w = __builtin_amdgcn_readfirstlane(tid >> 6);
    const int m0 = (bx >> 2) * 64;
    const int n0 = (bx & 3) * 64;
    const int wm = (w >> 1) * 32, wn = (w & 1) * 32;
    const int ln = lane & 15, kq = (lane >> 4) * 8;
    const int ar = tid >> 2, ac = (tid & 3) * 8;

    const __bf16* bsel = (w == 0) ? Bkh : (w == 1) ? Bkl : (w == 2) ? Bvh : Bvl;

    f32x4 ak[2][2], av[2][2];
#pragma unroll
    for (int i = 0; i < 2; ++i)
#pragma unroll
        for (int j = 0; j < 2; ++j) {
            ak[i][j] = (f32x4){0.f, 0.f, 0.f, 0.f};
            av[i][j] = (f32x4){0.f, 0.f, 0.f, 0.f};
        }

    for (int k0 = 0; k0 < EE; k0 += 32) {
        {
            bf16x8 h8, l8;
            cvt_split8(A + (size_t)(m0 + ar) * EE + k0 + ac, h8, l8);
            *(bf16x8*)&sAh[ar * SA_STRIDE + ac] = h8;
            *(bf16x8*)&sAl[ar * SA_STRIDE + ac] = l8;
            if (n0 == 0) {   // emit enc split once (blocks bx%4==0 cover all m)
                const size_t eo = (size_t)(m0 + ar) * EE + k0 + ac;
                *(bf16x8*)(enc_h + eo) = h8;
                *(bf16x8*)(enc_l + eo) = l8;
            }
        }
        {
            const __bf16* src = bsel + (size_t)(n0 + lane) * EE + k0;
            __bf16* dst = sB + (w * 64 + lane) * SA_STRIDE;
            *(bf16x8*)&dst[0]  = *(const bf16x8*)&src[0];
            *(bf16x8*)&dst[8]  = *(const bf16x8*)&src[8];
            *(bf16x8*)&dst[16] = *(const bf16x8*)&src[16];
            *(bf16x8*)&dst[24] = *(const bf16x8*)&src[24];
        }
        __syncthreads();

        bf16x8 ah[2], al[2];
#pragma unroll
        for (int mt = 0; mt < 2; ++mt) {
            ah[mt] = *(const bf16x8*)&sAh[(wm + mt * 16 + ln) * SA_STRIDE + kq];
            al[mt] = *(const bf16x8*)&sAl[(wm + mt * 16 + ln) * SA_STRIDE + kq];
        }
#pragma unroll
        for (int nt = 0; nt < 2; ++nt) {
            const int rowb = wn + nt * 16 + ln;
            bf16x8 bkh8 = *(const bf16x8*)&sB[(0 * 64 + rowb) * SA_STRIDE + kq];
            bf16x8 bkl8 = *(const bf16x8*)&sB[(1 * 64 + rowb) * SA_STRIDE + kq];
            bf16x8 bvh8 = *(const bf16x8*)&sB[(2 * 64 + rowb) * SA_STRIDE + kq];
            bf16x8 bvl8 = *(const bf16x8*)&sB[(3 * 64 + rowb) * SA_STRIDE + kq];
#pragma unroll
            for (int mt = 0; mt < 2; ++mt) {
                ak[mt][nt] = __builtin_amdgcn_mfma_f32_16x16x32_bf16(ah[mt], bkh8, ak[mt][nt], 0, 0, 0);
                ak[mt][nt] = __builtin_amdgcn_mfma_f32_16x16x32_bf16(al[mt], bkh8, ak[mt][nt], 0, 0, 0);
                ak[mt][nt] = __builtin_amdgcn_mfma_f32_16x16x32_bf16(ah[mt], bkl8, ak[mt][nt], 0, 0, 0);
                av[mt][nt] = __builtin_amdgcn_mfma_f32_16x16x32_bf16(ah[mt], bvh8, av[mt][nt], 0, 0, 0);
                av[mt][nt] = __builtin_amdgcn_mfma_f32_16x16x32_bf16(al[mt], bvh8, av[mt][nt], 0, 0, 0);
                av[mt][nt] = __builtin_amdgcn_mfma_f32_16x16x32_bf16(ah[mt], bvl8, av[mt][nt], 0, 0, 0);
            }
        }
        __syncthreads();
    }

    __bf16* eKh = (__bf16*)smem;
    __bf16* eKl = eKh + 5120;
    __bf16* eV  = eKl + 5120;

    const int rbase = (lane >> 4) * 4;
#pragma unroll
    for (int mt = 0; mt < 2; ++mt)
#pragma unroll
        for (int nt = 0; nt < 2; ++nt) {
            const int hloc = (w & 1) * 2 + nt;
            const int nl = wn + nt * 16 + ln;
#pragma unroll
            for (int r = 0; r < 4; ++r) {
                const int m = wm + mt * 16 + rbase + r;
                const float vk = ak[mt][nt][r];
                const __bf16 hk = (__bf16)vk;
                eKh[(hloc * 64 + m) * 20 + ln] = hk;
                eKl[(hloc * 64 + m) * 20 + ln] = (__bf16)(vk - (float)hk);
                eV[nl * 68 + m] = (__bf16)av[mt][nt][r];
            }
        }
    __syncthreads();

    const int b = m0 >> 9;
    const int pbase = m0 & (PP - 1);
    {
        const int hl = tid >> 6, p = tid & 63;
        const int hg = (n0 >> 4) + hl;
        const size_t dst = (((size_t)b * HH + hg) * PP + pbase + p) * KD;
        const int base = (hl * 64 + p) * 20;
        uint2 a0 = *(const uint2*)&eKh[base + 0];
        uint2 a1 = *(const uint2*)&eKh[base + 4];
        uint2 a2 = *(const uint2*)&eKh[base + 8];
        uint2 a3 = *(const uint2*)&eKh[base + 12];
        *(uint4*)(Khi + dst)     = make_uint4(a0.x, a0.y, a1.x, a1.y);
        *(uint4*)(Khi + dst + 8) = make_uint4(a2.x, a2.y, a3.x, a3.y);
        uint2 c0 = *(const uint2*)&eKl[base + 0];
        uint2 c1 = *(const uint2*)&eKl[base + 4];
        uint2 c2 = *(const uint2*)&eKl[base + 8];
        uint2 c3 = *(const uint2*)&eKl[base + 12];
        *(uint4*)(Klo + dst)     = make_uint4(c0.x, c0.y, c1.x, c1.y);
        *(uint4*)(Klo + dst + 8) = make_uint4(c2.x, c2.y, c3.x, c3.y);
    }
    {
        const int n = tid >> 2, qq = tid & 3;
        const int ng = n0 + n, hg = ng >> 4, kk = ng & 15;
        const int base = n * 68 + qq * 16;
        uint2 v0 = *(const uint2*)&eV[base + 0];
        uint2 v1 = *(const uint2*)&eV[base + 4];
        uint2 v2 = *(const uint2*)&eV[base + 8];
        uint2 v3 = *(const uint2*)&eV[base + 12];
        const size_t dst = ((((size_t)b * HH + hg) * KD + kk) * PP) + pbase + qq * 16;
        *(uint4*)(Vt + dst)     = make_uint4(v0.x, v0.y, v1.x, v1.y);
        *(uint4*)(Vt + dst + 8) = make_uint4(v2.x, v2.y, v3.x, v3.y);
    }
}

// ---------------------------------------------------------------------------
// LDS-staged Q projection body (verified round 10).
// ---------------------------------------------------------------------------
__device__ inline void qproj_body(int bx, int tid, unsigned char* smem,
                                  const float* __restrict__ in1,
                                  const float* __restrict__ in2,
                                  const float* __restrict__ ct,
                                  const __bf16* __restrict__ Bh,
                                  const __bf16* __restrict__ Bl,
                                  const float* __restrict__ WqFull,
                                  __bf16* __restrict__ Qhi,
                                  __bf16* __restrict__ Qlo)
{
    __bf16* sAh = (__bf16*)smem;
    __bf16* sAl = sAh + 64 * SA_STRIDE;
    __bf16* sB  = sAl + 64 * SA_STRIDE;

    const int lane = tid & 63;
    const int w = __builtin_amdgcn_readfirstlane(tid >> 6);
    const int m0 = (bx >> 2) * 64;
    const int n0 = (bx & 3) * 64;
    const int wm = (w >> 1) * 32, wn = (w & 1) * 32;
    const int ln = lane & 15, kq = (lane >> 4) * 8;
    const int ar = tid >> 2, ac = (tid & 3) * 8;
    const int b = m0 >> 9;
    const float* WqLast = WqFull + (size_t)512 * HK;

    f32x4 acc[2][2];
#pragma unroll
    for (int i = 0; i < 2; ++i)
#pragma unroll
        for (int j = 0; j < 2; ++j) acc[i][j] = (f32x4){0.f, 0.f, 0.f, 0.f};

    for (int k0 = 0; k0 < 512; k0 += 32) {
        {
            const float* ap = (k0 < 256)
                ? in1 + (size_t)b * EE + k0 + ac
                : in2 + (size_t)(m0 + ar) * EE + (k0 - 256) + ac;
            bf16x8 h8, l8;
            cvt_split8(ap, h8, l8);
            *(bf16x8*)&sAh[ar * SA_STRIDE + ac] = h8;
            *(bf16x8*)&sAl[ar * SA_STRIDE + ac] = l8;
        }
        {
            const int mat = w >> 1;
            const int row = (w & 1) * 32 + (lane >> 1);
            const int half = (lane & 1) * 16;
            const __bf16* src = (mat ? Bl : Bh) + ((size_t)(n0 + row) << 9) + k0 + half;
            __bf16* dst = sB + (mat * 64 + row) * SA_STRIDE + half;
            *(bf16x8*)&dst[0] = *(const bf16x8*)&src[0];
            *(bf16x8*)&dst[8] = *(const bf16x8*)&src[8];
        }
        __syncthreads();

        bf16x8 ah[2], al[2];
#pragma unroll
        for (int mt = 0; mt < 2; ++mt) {
            ah[mt] = *(const bf16x8*)&sAh[(wm + mt * 16 + ln) * SA_STRIDE + kq];
            al[mt] = *(const bf16x8*)&sAl[(wm + mt * 16 + ln) * SA_STRIDE + kq];
        }
#pragma unroll
        for (int nt = 0; nt < 2; ++nt) {
            const int rowb = wn + nt * 16 + ln;
            bf16x8 bh8 = *(const bf16x8*)&sB[(0 * 64 + rowb) * SA_STRIDE + kq];
            bf16x8 bl8 = *(const bf16x8*)&sB[(1 * 64 + rowb) * SA_STRIDE + kq];
#pragma unroll
            for (int mt = 0; mt < 2; ++mt) {
                acc[mt][nt] = __builtin_amdgcn_mfma_f32_16x16x32_bf16(ah[mt], bh8, acc[mt][nt], 0, 0, 0);
                acc[mt][nt] = __builtin_amdgcn_mfma_f32_16x16x32_bf16(al[mt], bh8, acc[mt][nt], 0, 0, 0);
                acc[mt][nt] = __builtin_amdgcn_mfma_f32_16x16x32_bf16(ah[mt], bl8, acc[mt][nt], 0, 0, 0);
            }
        }
        __syncthreads();
    }

    __bf16* eQh = (__bf16*)smem;
    __bf16* eQl = eQh + 5120;

    const int rbase = (lane >> 4) * 4;
#pragma unroll
    for (int mt = 0; mt < 2; ++mt)
#pragma unroll
        for (int nt = 0; nt < 2; ++nt) {
            const int hloc = (w & 1) * 2 + nt;
            const int ng = n0 + wn + nt * 16 + ln;
            const float wq = WqLast[ng];
#pragma unroll
            for (int r = 0; r < 4; ++r) {
                const int m = wm + mt * 16 + rbase + r;
                const float v = acc[mt][nt][r] + ct[m0 + m] * wq;
                const __bf16 h = (__bf16)v;
                eQh[(hloc * 64 + m) * 20 + ln] = h;
                eQl[(hloc * 64 + m) * 20 + ln] = (__bf16)(v - (float)h);
            }
        }
    __syncthreads();

    {
        const int hl = tid >> 6, p = tid & 63;
        const int hg = (n0 >> 4) + hl;
        const int g = (m0 & (GG - 1)) + p;
        const size_t dst = (((size_t)b * HH + hg) * GG + g) * KD;
        const int base = (hl * 64 + p) * 20;
        uint2 a0 = *(const uint2*)&eQh[base + 0];
        uint2 a1 = *(const uint2*)&eQh[base + 4];
        uint2 a2 = *(const uint2*)&eQh[base + 8];
        uint2 a3 = *(const uint2*)&eQh[base + 12];
        *(uint4*)(Qhi + dst)     = make_uint4(a0.x, a0.y, a1.x, a1.y);
        *(uint4*)(Qhi + dst + 8) = make_uint4(a2.x, a2.y, a3.x, a3.y);
        uint2 c0 = *(const uint2*)&eQl[base + 0];
        uint2 c1 = *(const uint2*)&eQl[base + 4];
        uint2 c2 = *(const uint2*)&eQl[base + 8];
        uint2 c3 = *(const uint2*)&eQl[base + 12];
        *(uint4*)(Qlo + dst)     = make_uint4(c0.x, c0.y, c1.x, c1.y);
        *(uint4*)(Qlo + dst + 8) = make_uint4(c2.x, c2.y, c3.x, c3.y);
    }
}

// ---------------------------------------------------------------------------
// Fused K/V + Q projections: 1024 blocks.
// ---------------------------------------------------------------------------
__global__ __launch_bounds__(256, 2) void fused_proj(const float* __restrict__ enc,
                                                     const __bf16* __restrict__ Bkh,
                                                     const __bf16* __restrict__ Bkl,
                                                     const __bf16* __restrict__ Bvh,
                                                     const __bf16* __restrict__ Bvl,
                                                     __bf16* __restrict__ Khi,
                                                     __bf16* __restrict__ Klo,
                                                     __bf16* __restrict__ Vt,
                                                     __bf16* __restrict__ enc_h,
                                                     __bf16* __restrict__ enc_l,
                                                     const float* __restrict__ in1,
                                                     const float* __restrict__ in2,
                                                     const float* __restrict__ ct,
                                                     const __bf16* __restrict__ Bqh,
                                                     const __bf16* __restrict__ Bql,
                                                     const float* __restrict__ WqFull,
                                                     __bf16* __restrict__ Qhi,
                                                     __bf16* __restrict__ Qlo)
{
    __shared__ __align__(16) unsigned char smem[SMEM_BYTES];
    const int id = blockIdx.x;
    if (id < 512)
        kvproj_body(id, threadIdx.x, smem, enc, Bkh, Bkl, Bvh, Bvl, Khi, Klo, Vt, enc_h, enc_l);
    else
        qproj_body(id - 512, threadIdx.x, smem, in1, in2, ct, Bqh, Bql, WqFull, Qhi, Qlo);
}

// ---------------------------------------------------------------------------
// attn_v8 (verified round 8): one wave per (b, h, 32 g); 32x32x16 QK,
// sum-only flash, per-wave LDS P staging, 16x16x32 PV; bf16 hi/lo output.
// ---------------------------------------------------------------------------
__global__ __launch_bounds__(256, 4) void attn_v8(const __bf16* __restrict__ Qhi,
                                                  const __bf16* __restrict__ Qlo,
                                                  const __bf16* __restrict__ Khi,
                                                  const __bf16* __restrict__ Klo,
                                                  const __bf16* __restrict__ Vt,
                                                  const float* __restrict__ mask,
                                                  __bf16* __restrict__ Ath,
                                                  __bf16* __restrict__ Atl)
{
    __shared__ __align__(16) __bf16 sP[4][32][40];
    __shared__ float srs[4][32];

    const int t = threadIdx.x;
    const int lane = t & 63;
    const int w = __builtin_amdgcn_readfirstlane(t >> 6);
    const int g0 = blockIdx.x * 32;
    const int h = blockIdx.y * 4 + w;
    const int b = blockIdx.z;
    const int ln32 = lane & 31;
    const int half = lane >> 5;
    const int ln16 = lane & 15;
    const int quad = (lane >> 4) & 3;

    const size_t qbase = (((size_t)b * HH + h) * GG + g0) * KD;
    const size_t kbase = ((size_t)b * HH + h) * PP * KD;
    const size_t vbase = ((size_t)b * HH + h) * KD * PP;
    const float* mbase = mask + ((size_t)(b * GG + g0)) * PP;

    bf16x8 qah = *(const bf16x8*)(Qhi + qbase + (size_t)ln32 * KD + half * 8);
    bf16x8 qal = *(const bf16x8*)(Qlo + qbase + (size_t)ln32 * KD + half * 8);

    float rs[16];
#pragma unroll
    for (int r = 0; r < 16; ++r) rs[r] = 0.f;
    f32x4 o0 = (f32x4){0.f, 0.f, 0.f, 0.f};
    f32x4 o1 = (f32x4){0.f, 0.f, 0.f, 0.f};

#pragma unroll 2
    for (int pc = 0; pc < 16; ++pc) {
        const int pb = pc * 32;
        const size_t ko = kbase + (size_t)(pb + ln32) * KD + half * 8;
        bf16x8 kh = *(const bf16x8*)(Khi + ko);
        bf16x8 kl = *(const bf16x8*)(Klo + ko);

        f32x16 s = (f32x16){0.f, 0.f, 0.f, 0.f, 0.f, 0.f, 0.f, 0.f,
                            0.f, 0.f, 0.f, 0.f, 0.f, 0.f, 0.f, 0.f};
        s = __builtin_amdgcn_mfma_f32_32x32x16_bf16(qah, kh, s, 0, 0, 0);
        s = __builtin_amdgcn_mfma_f32_32x32x16_bf16(qal, kh, s, 0, 0, 0);
        s = __builtin_amdgcn_mfma_f32_32x32x16_bf16(qah, kl, s, 0, 0, 0);

#pragma unroll
        for (int r = 0; r < 16; ++r) {
            const int row = (r & 3) + 8 * (r >> 2) + 4 * half;
            const float m = mbase[(size_t)row * PP + pb + ln32];
            const float e = __expf(s[r] * 0.25f + m);
            rs[r] += e;
            sP[w][row][ln32] = (__bf16)e;
        }

        bf16x8 vb = *(const bf16x8*)(Vt + vbase + (size_t)ln16 * PP + pb + quad * 8);
        bf16x8 p0 = *(const bf16x8*)&sP[w][ln16][quad * 8];
        bf16x8 p1 = *(const bf16x8*)&sP[w][16 + ln16][quad * 8];
        o0 = __builtin_amdgcn_mfma_f32_16x16x32_bf16(p0, vb, o0, 0, 0, 0);
        o1 = __builtin_amdgcn_mfma_f32_16x16x32_bf16(p1, vb, o1, 0, 0, 0);
    }

#pragma unroll
    for (int r = 0; r < 16; ++r) {
#pragma unroll
        for (int mm = 1; mm < 32; mm <<= 1) rs[r] += __shfl_xor(rs[r], mm);
    }
    if (ln32 == 0) {
#pragma unroll
        for (int r = 0; r < 16; ++r)
            srs[w][(r & 3) + 8 * (r >> 2) + 4 * half] = rs[r];
    }

#pragma unroll
    for (int t2 = 0; t2 < 2; ++t2) {
        const f32x4 oc = t2 ? o1 : o0;
#pragma unroll
        for (int r = 0; r < 4; ++r) {
            const int grow = t2 * 16 + quad * 4 + r;
            const float v = oc[r] / srs[w][grow];
            const __bf16 hv = (__bf16)v;
            const size_t oo = ((size_t)(b * GG + g0 + grow)) * HK + h * KD + ln16;
            Ath[oo] = hv;
            Atl[oo] = (__bf16)(v - (float)hv);
        }
    }
}

// ---------------------------------------------------------------------------
// Pointer head v4: output projection FUSED in. Per block (b, 32 g):
// phase 1: wave w computes mh[32g x 32n] tile (n = w*32..) = Att @ WcT + bias
//          via split-bf16 32x32x16 MFMA; store hi/lo into LDS.
// phase 2: verified v3 pointer math, A-fragments from LDS.
// XCD-pinned (b = id & 15). 512 thr = 8 waves x 64 p.
// ---------------------------------------------------------------------------
__global__ __launch_bounds__(512) void pointer_v4(const __bf16* __restrict__ Ath,
                                                  const __bf16* __restrict__ Atl,
                                                  const __bf16* __restrict__ wct_h,
                                                  const __bf16* __restrict__ wct_l,
                                                  const float* __restrict__ bias,
                                                  const __bf16* __restrict__ enc_hi,
                                                  const __bf16* __restrict__ enc_lo,
                                                  const float* __restrict__ mask,
                                                  float* __restrict__ out)
{
    __shared__ __align__(16) __bf16 smh_h[32][264];  // 16.5 KB, 528B rows (16B-aligned)
    __shared__ __align__(16) __bf16 smh_l[32][264];
    __shared__ float swsum[8][32];

    const int t = threadIdx.x;
    const int lane = t & 63;
    const int w = __builtin_amdgcn_readfirstlane(t >> 6);  // 0..7
    const int id = blockIdx.x;
    const int b = id & 15;                 // XCD pin: id%8 == b%8
    const int g0 = (id >> 4) * 32;
    const int ln32 = lane & 31;
    const int half = lane >> 5;

    // ---- phase 1: mh tile (32 g x 32 n), n-slice per wave --------------
    {
        const int n0w = w * 32;
        const size_t aarow = ((size_t)(b * GG + g0 + ln32)) * HK + half * 8;
        const size_t wrow  = ((size_t)(n0w + ln32)) * EE + half * 8;

        f32x16 macc = (f32x16){0.f, 0.f, 0.f, 0.f, 0.f, 0.f, 0.f, 0.f,
                               0.f, 0.f, 0.f, 0.f, 0.f, 0.f, 0.f, 0.f};
        for (int kc = 0; kc < EE; kc += 16) {
            bf16x8 ah = *(const bf16x8*)(Ath + aarow + kc);
            bf16x8 al = *(const bf16x8*)(Atl + aarow + kc);
            bf16x8 bh = *(const bf16x8*)(wct_h + wrow + kc);
            bf16x8 bl = *(const bf16x8*)(wct_l + wrow + kc);
            macc = __builtin_amdgcn_mfma_f32_32x32x16_bf16(ah, bh, macc, 0, 0, 0);
            macc = __builtin_amdgcn_mfma_f32_32x32x16_bf16(al, bh, macc, 0, 0, 0);
            macc = __builtin_amdgcn_mfma_f32_32x32x16_bf16(ah, bl, macc, 0, 0, 0);
        }
        const float bs = bias[n0w + ln32];
#pragma unroll
        for (int r = 0; r < 16; ++r) {
            const int row = (r & 3) + 8 * (r >> 2) + 4 * half;  // g-local
            const float v = macc[r] + bs;
            const __bf16 h = (__bf16)v;
            smh_h[row][n0w + ln32] = h;
            smh_l[row][n0w + ln32] = (__bf16)(v - (float)h);
        }
    }
    __syncthreads();

    // ---- phase 2: S = mh @ enc^T, clip/mask/softmax (verified v3) ------
    const size_t brow = ((size_t)(b * PP + w * 64 + ln32)) * EE + half * 8;

    f32x16 acc[2];
#pragma unroll
    for (int pt = 0; pt < 2; ++pt)
        acc[pt] = (f32x16){0.f, 0.f, 0.f, 0.f, 0.f, 0.f, 0.f, 0.f,
                           0.f, 0.f, 0.f, 0.f, 0.f, 0.f, 0.f, 0.f};

    for (int kc = 0; kc < EE; kc += 16) {
        bf16x8 ah = *(const bf16x8*)&smh_h[ln32][kc + half * 8];
        bf16x8 al = *(const bf16x8*)&smh_l[ln32][kc + half * 8];
#pragma unroll
        for (int pt = 0; pt < 2; ++pt) {
            const size_t bo = brow + (size_t)pt * 32 * EE + kc;
            bf16x8 bh = *(const bf16x8*)(enc_hi + bo);
            bf16x8 bl = *(const bf16x8*)(enc_lo + bo);
            acc[pt] = __builtin_amdgcn_mfma_f32_32x32x16_bf16(ah, bh, acc[pt], 0, 0, 0);
            acc[pt] = __builtin_amdgcn_mfma_f32_32x32x16_bf16(al, bh, acc[pt], 0, 0, 0);
            acc[pt] = __builtin_amdgcn_mfma_f32_32x32x16_bf16(ah, bl, acc[pt], 0, 0, 0);
        }
    }

    float rsum[16];
#pragma unroll
    for (int r = 0; r < 16; ++r) rsum[r] = 0.f;
#pragma unroll
    for (int pt = 0; pt < 2; ++pt)
#pragma unroll
        for (int r = 0; r < 16; ++r) {
            const int row = (r & 3) + 8 * (r >> 2) + 4 * half;
            float s = acc[pt][r] * 0.0625f;              // 1/sqrt(256)
            s = fminf(9.f, fmaxf(-9.f, s));
            const float e2 = __expf(2.f * s);
            const float th = (e2 - 1.f) / (e2 + 1.f);    // tanh(s)
            const float m = mask[((size_t)(b * GG + g0 + row)) * PP + w * 64 + pt * 32 + ln32];
            const float e = __expf(10.f * th + m);       // bounded by e^10
            acc[pt][r] = e;
            rsum[r] += e;
        }

#pragma unroll
    for (int r = 0; r < 16; ++r) {
        rsum[r] += __shfl_xor(rsum[r], 1);
        rsum[r] += __shfl_xor(rsum[r], 2);
        rsum[r] += __shfl_xor(rsum[r], 4);
        rsum[r] += __shfl_xor(rsum[r], 8);
        rsum[r] += __shfl_xor(rsum[r], 16);
    }
    if (ln32 == 0) {
#pragma unroll
        for (int r = 0; r < 16; ++r)
            swsum[w][(r & 3) + 8 * (r >> 2) + 4 * half] = rsum[r];
    }
    __syncthreads();

    float inv[16];
#pragma unroll
    for (int r = 0; r < 16; ++r) {
        const int row = (r & 3) + 8 * (r >> 2) + 4 * half;
        float tot = 0.f;
#pragma unroll
        for (int wv = 0; wv < 8; ++wv) tot += swsum[wv][row];
        inv[r] = 1.f / tot;
    }

#pragma unroll
    for (int pt = 0; pt < 2; ++pt)
#pragma unroll
        for (int r = 0; r < 16; ++r) {
            const int row = (r & 3) + 8 * (r >> 2) + 4 * half;
            out[((size_t)(b * GG + g0 + row)) * PP + w * 64 + pt * 32 + ln32] =
                acc[pt][r] * inv[r];
        }
}

// ---------------------------------------------------------------------------
extern "C" void kernel_launch(void* const* d_in, const int* in_sizes, int n_in,
                              void* d_out, int out_size, void* d_ws, size_t ws_size,
                              hipStream_t stream)
{
    const float* in1  = (const float*)d_in[0];
    const float* in2  = (const float*)d_in[1];
    const float* ct   = (const float*)d_in[2];
    const float* mask = (const float*)d_in[3];
    const float* enc  = (const float*)d_in[4];
    const float* Wq   = (const float*)d_in[5];
    const float* Wk   = (const float*)d_in[6];
    const float* Wv   = (const float*)d_in[7];
    const float* Wcw  = (const float*)d_in[8];
    const float* Wcb  = (const float*)d_in[9];
    float* out = (float*)d_out;

    // ws is 256 MB (fill evidence, round 12) — use disjoint regions, no overlays.
    const size_t SEG = (size_t)BB * GG * HK;  // 2M bf16 elements = 4 MB
    __bf16* base = (__bf16*)d_ws;
    __bf16* Khi   = base + 0 * SEG;
    __bf16* Klo   = base + 1 * SEG;
    __bf16* Vt    = base + 2 * SEG;
    __bf16* Qhi   = base + 3 * SEG;
    __bf16* Qlo   = base + 4 * SEG;
    __bf16* Ath   = base + 5 * SEG;
    __bf16* Atl   = base + 6 * SEG;
    __bf16* enc_h = base + 7 * SEG;
    __bf16* enc_l = base + 8 * SEG;
    __bf16* wkt_h = base + 9 * SEG;
    __bf16* wkt_l = wkt_h + 65536;
    __bf16* wvt_h = wkt_l + 65536;
    __bf16* wvt_l = wvt_h + 65536;
    __bf16* wqt_h = wvt_l + 65536;
    __bf16* wqt_l = wqt_h + 131072;
    __bf16* wct_h = wqt_l + 131072;
    __bf16* wct_l = wct_h + 65536;

    const dim3 blk(256);

    weight_prep<<<dim3(1280), blk, 0, stream>>>(Wk, Wv, Wq, Wcw,
                                                wkt_h, wkt_l, wvt_h, wvt_l,
                                                wqt_h, wqt_l, wct_h, wct_l);

    fused_proj<<<dim3(1024), blk, 0, stream>>>(enc, wkt_h, wkt_l, wvt_h, wvt_l,
                                               Khi, Klo, Vt, enc_h, enc_l,
                                               in1, in2, ct, wqt_h, wqt_l, Wq,
                                               Qhi, Qlo);

    attn_v8<<<dim3(GG / 32, HH / 4, BB), blk, 0, stream>>>(Qhi, Qlo, Khi, Klo, Vt, mask, Ath, Atl);

    pointer_v4<<<dim3(256), dim3(512), 0, stream>>>(Ath, Atl, wct_h, wct_l, Wcb,
                                                    enc_h, enc_l, mask, out);
}